// Round 12
// baseline (177.153 us; speedup 1.0000x reference)
//
#include <hip/hip_runtime.h>

#define H_ 160
#define W_ 160
#define HW_ (H_ * W_)
#define NPIX (8 * HW_)   // 204800 pixels

// ============================================================================
// R12: R11 fused-bf16 + occupancy/conflict surgery.
//  - ONE shared weight LDS buffer (wo dead after stage 1): fill w_off, stage1,
//    sync, refill with w_dcn, sync, stage2. LDS 46.6 -> 28.1 KB => 5 blk/CU
//    (R11: 2 blk/CU, occupancy 24%, everything latency-starved).
//  - unit-wise b128 weight fill (one 16B B-frag unit per lane-iter): kills the
//    2.76M bank conflicts of R11's scattered ushort fill.
//  - f32x4 transpose writes (D-rows contiguous per reg-quad).
// Numerics identical to R9/R11 (verified): bf16 MFMA 32x32x16, packed-f32
// bilinear combine, layouts A[m=lane&31][k=(lane>>5)*8+j], D col n=lane&31,
// row=(reg&3)+8*(reg>>2)+4*(lane>>5).
// ============================================================================

typedef __attribute__((ext_vector_type(8)))  short  short8;   // 8 bf16
typedef __attribute__((ext_vector_type(4)))  float  f32x4;
typedef __attribute__((ext_vector_type(2)))  float  f32x2;
typedef __attribute__((ext_vector_type(16))) float  f32x16;
typedef __attribute__((ext_vector_type(4)))  unsigned u32x4;

__device__ __forceinline__ unsigned short bf16_rne(float f) {
    unsigned u = __float_as_uint(f);
    u += 0x7fffu + ((u >> 16) & 1u);
    return (unsigned short)(u >> 16);
}
__device__ __forceinline__ unsigned pack2_bf16(float a, float b) {
    unsigned ua = __float_as_uint(a); ua += 0x7fffu + ((ua >> 16) & 1u);
    unsigned ub = __float_as_uint(b); ub += 0x7fffu + ((ub >> 16) & 1u);
    return (ua >> 16) | (ub & 0xffff0000u);
}
__device__ __forceinline__ f32x2 up2(unsigned u) {
    f32x2 r;
    r.x = __uint_as_float(u << 16);
    r.y = __uint_as_float(u & 0xffff0000u);
    return r;
}

// ---- x (B,32,H,W) fp32 -> xT (B,H,W,32) bf16 -------------------------------
__global__ __launch_bounds__(256) void nhwc_bf16(
    const float* __restrict__ x, unsigned short* __restrict__ xT)
{
    const int pix = blockIdx.x * 256 + threadIdx.x;
    const int p = pix % HW_;
    const int b = pix / HW_;
    const float* __restrict__ src = x + (size_t)b * 32 * HW_ + p;
    unsigned* __restrict__ dst = (unsigned*)(xT + (size_t)pix * 32);
    #pragma unroll
    for (int g = 0; g < 16; ++g)
        dst[g] = pack2_bf16(src[(2 * g) * HW_], src[(2 * g + 1) * HW_]);
}

// ---- fused: offset conv + bilinear sampling + dcn GEMM + ReLU --------------
__global__ __launch_bounds__(256, 5) void dcn_fused(
    const unsigned short* __restrict__ xT,   // (8,160,160,32) bf16
    const float* __restrict__ w_off,         // (18, 32, 3, 3)
    const float* __restrict__ b_off,         // (18,)
    const float* __restrict__ w_dcn,         // (32, 32, 3, 3)
    float* __restrict__ out)                 // (8, 32, 160, 160)
{
    // lane-linear B-frags: unit = (tap*2 + kstep)*64 + col + 32*kg,
    // 8 bf16 (16 B) each. ONE buffer, refilled between stages.
    __shared__ __align__(16) unsigned short wsh[9 * 128 * 8];   // 18 KB
    __shared__ float offl[4 * 594];   // per-wave offset transpose, row pad 33
    __shared__ float bl[32];
    const int tid = threadIdx.x;

    // ---- fill stage-1 weights (w_off), one b128 unit per lane-iter --------
    for (int u = tid; u < 1152; u += 256) {
        const int tap = u >> 7, rem = u & 127;
        const int s = rem >> 6, rem2 = rem & 63;
        const int kg = rem2 >> 5, col = rem2 & 31;
        const int cb = s * 16 + kg * 8;
        u32x4 v = {0u, 0u, 0u, 0u};
        if (col < 18) {
            const float* __restrict__ wp = w_off + (size_t)(col * 32 + cb) * 9 + tap;
            v.x = pack2_bf16(wp[0 * 9], wp[1 * 9]);
            v.y = pack2_bf16(wp[2 * 9], wp[3 * 9]);
            v.z = pack2_bf16(wp[4 * 9], wp[5 * 9]);
            v.w = pack2_bf16(wp[6 * 9], wp[7 * 9]);
        }
        *(u32x4*)(wsh + u * 8) = v;
    }
    if (tid < 32) bl[tid] = (tid < 18) ? b_off[tid] : 0.0f;
    __syncthreads();

    const int wave = tid >> 6, lane = tid & 63;
    const int n = lane & 31;          // pixel (A-row m) == out channel (D-col)
    const int hh = lane >> 5;         // k-group
    const int pixbase = blockIdx.x * 128 + wave * 32;
    const int pix = pixbase + n;
    const int w = pix % W_, h = (pix / W_) % H_, b = pix / HW_;
    const unsigned short* __restrict__ xb = xT + (size_t)b * HW_ * 32 + hh * 8;

    // ---------------- stage 1: offset conv GEMM ----------------------------
    {
        f32x16 acc = {};
        const u32x4 z4 = {0u, 0u, 0u, 0u};
        #pragma unroll
        for (int tap = 0; tap < 9; ++tap) {
            const int yy = h - 1 + tap / 3;
            const int xx = w - 1 + tap % 3;
            const bool valid = (yy >= 0) && (yy < H_) && (xx >= 0) && (xx < W_);
            const int idx = min(max(yy, 0), H_ - 1) * W_ + min(max(xx, 0), W_ - 1);
            const unsigned short* __restrict__ px_ = xb + (size_t)idx * 32;
            u32x4 l0 = *(const u32x4*)(px_);
            u32x4 l1 = *(const u32x4*)(px_ + 16);
            l0 = valid ? l0 : z4;
            l1 = valid ? l1 : z4;
            const short8 a0 = __builtin_bit_cast(short8, l0);
            const short8 a1 = __builtin_bit_cast(short8, l1);
            const short8 b0 = *(const short8*)(wsh + ((tap * 2 + 0) * 64 + lane) * 8);
            const short8 b1 = *(const short8*)(wsh + ((tap * 2 + 1) * 64 + lane) * 8);
            acc = __builtin_amdgcn_mfma_f32_32x32x16_bf16(a0, b0, acc, 0, 0, 0);
            acc = __builtin_amdgcn_mfma_f32_32x32x16_bf16(a1, b1, acc, 0, 0, 0);
        }
        // D-layout -> per-wave LDS transpose: [j(18)][pix(32)], row pad 33.
        // rows (r&3)+8g+4hh contiguous per reg-quad -> f32x4 writes.
        float* __restrict__ owp = offl + wave * 594;
        if (n < 18) {
            const float bia = bl[n];
            #pragma unroll
            for (int g = 0; g < 4; ++g) {
                f32x4 r;
                #pragma unroll
                for (int i = 0; i < 4; ++i) r[i] = acc[g * 4 + i] + bia;
                *(f32x4*)(owp + n * 33 + 8 * g + 4 * hh) = r;
            }
        }
    }
    __syncthreads();   // stage-1 reads + transpose writes complete

    // ---- refill shared buffer with stage-2 weights (w_dcn) ----------------
    for (int u = tid; u < 1152; u += 256) {
        const int tap = u >> 7, rem = u & 127;
        const int s = rem >> 6, rem2 = rem & 63;
        const int kg = rem2 >> 5, col = rem2 & 31;
        const int cb = s * 16 + kg * 8;
        const float* __restrict__ wp = w_dcn + (size_t)(col * 32 + cb) * 9 + tap;
        u32x4 v;
        v.x = pack2_bf16(wp[0 * 9], wp[1 * 9]);
        v.y = pack2_bf16(wp[2 * 9], wp[3 * 9]);
        v.z = pack2_bf16(wp[4 * 9], wp[5 * 9]);
        v.w = pack2_bf16(wp[6 * 9], wp[7 * 9]);
        *(u32x4*)(wsh + u * 8) = v;
    }
    __syncthreads();

    // ---------------- stage 2: bilinear sampling + dcn GEMM ----------------
    const float* __restrict__ ow = offl + wave * 594;
    f32x16 acc = {};

    #pragma unroll
    for (int tap = 0; tap < 9; ++tap) {
        const float dy = ow[(2 * tap) * 33 + n];
        const float dx = ow[(2 * tap + 1) * 33 + n];
        const float py = (float)(h - 1 + tap / 3) + dy;
        const float px = (float)(w - 1 + tap % 3) + dx;
        const float fy0 = floorf(py), fx0 = floorf(px);
        const float wy1 = py - fy0, wx1 = px - fx0;
        const float wy0 = 1.0f - wy1, wx0 = 1.0f - wx1;
        const int y0 = (int)fy0, x0 = (int)fx0;
        const bool vy0 = (y0 >= 0) && (y0 < H_);
        const bool vy1 = (y0 + 1 >= 0) && (y0 + 1 < H_);
        const bool vx0 = (x0 >= 0) && (x0 < W_);
        const bool vx1 = (x0 + 1 >= 0) && (x0 + 1 < W_);
        const float w00 = (vy0 && vx0) ? wy0 * wx0 : 0.0f;
        const float w01 = (vy0 && vx1) ? wy0 * wx1 : 0.0f;
        const float w10 = (vy1 && vx0) ? wy1 * wx0 : 0.0f;
        const float w11 = (vy1 && vx1) ? wy1 * wx1 : 0.0f;
        const int yc0 = min(max(y0, 0), H_ - 1), yc1 = min(max(y0 + 1, 0), H_ - 1);
        const int xc0 = min(max(x0, 0), W_ - 1), xc1 = min(max(x0 + 1, 0), W_ - 1);

        const unsigned short* __restrict__ pA = xb + (size_t)(yc0 * W_ + xc0) * 32;
        const unsigned short* __restrict__ pB = xb + (size_t)(yc0 * W_ + xc1) * 32;
        const unsigned short* __restrict__ pC = xb + (size_t)(yc1 * W_ + xc0) * 32;
        const unsigned short* __restrict__ pD = xb + (size_t)(yc1 * W_ + xc1) * 32;
        // 8 independent 16B gathers (2 k-steps x 4 corners)
        const u32x4 A0 = *(const u32x4*)(pA);      const u32x4 A1 = *(const u32x4*)(pA + 16);
        const u32x4 B0 = *(const u32x4*)(pB);      const u32x4 B1 = *(const u32x4*)(pB + 16);
        const u32x4 C0 = *(const u32x4*)(pC);      const u32x4 C1 = *(const u32x4*)(pC + 16);
        const u32x4 D0 = *(const u32x4*)(pD);      const u32x4 D1 = *(const u32x4*)(pD + 16);

        #define COMB(a, bb, cc, dd) ({ \
            const f32x2 v = up2(a) * w00 + up2(bb) * w01 + up2(cc) * w10 + up2(dd) * w11; \
            pack2_bf16(v.x, v.y); })
        u32x4 av0, av1;
        av0.x = COMB(A0.x, B0.x, C0.x, D0.x);
        av0.y = COMB(A0.y, B0.y, C0.y, D0.y);
        av0.z = COMB(A0.z, B0.z, C0.z, D0.z);
        av0.w = COMB(A0.w, B0.w, C0.w, D0.w);
        av1.x = COMB(A1.x, B1.x, C1.x, D1.x);
        av1.y = COMB(A1.y, B1.y, C1.y, D1.y);
        av1.z = COMB(A1.z, B1.z, C1.z, D1.z);
        av1.w = COMB(A1.w, B1.w, C1.w, D1.w);
        #undef COMB

        const short8 a0 = __builtin_bit_cast(short8, av0);
        const short8 a1 = __builtin_bit_cast(short8, av1);
        const short8 b0 = *(const short8*)(wsh + ((tap * 2 + 0) * 64 + lane) * 8);
        const short8 b1 = *(const short8*)(wsh + ((tap * 2 + 1) * 64 + lane) * 8);
        acc = __builtin_amdgcn_mfma_f32_32x32x16_bf16(a0, b0, acc, 0, 0, 0);
        acc = __builtin_amdgcn_mfma_f32_32x32x16_bf16(a1, b1, acc, 0, 0, 0);
    }

    // D: col o = n; rows = pixels pixbase + g*8 + 4*hh + i
    float* __restrict__ ob = out + (size_t)b * 32 * HW_ + (size_t)n * HW_
                           + (pixbase - b * HW_) + 4 * hh;
    #pragma unroll
    for (int g = 0; g < 4; ++g) {
        f32x4 r;
        #pragma unroll
        for (int i = 0; i < 4; ++i) r[i] = fmaxf(acc[g * 4 + i], 0.0f);
        *(f32x4*)(ob + g * 8) = r;
    }
}

extern "C" void kernel_launch(void* const* d_in, const int* in_sizes, int n_in,
                              void* d_out, int out_size, void* d_ws, size_t ws_size,
                              hipStream_t stream) {
    const float* x     = (const float*)d_in[0];
    const float* w_off = (const float*)d_in[1];
    const float* b_off = (const float*)d_in[2];
    const float* w_dcn = (const float*)d_in[3];
    float* out = (float*)d_out;

    unsigned short* xT = (unsigned short*)d_ws;   // 13.1 MB bf16 NHWC

    nhwc_bf16<<<800, 256, 0, stream>>>(x, xT);
    dcn_fused<<<1600, 256, 0, stream>>>(xT, w_off, b_off, w_dcn, out);
}

// Round 13
// 176.587 us; speedup vs baseline: 1.0032x; 1.0032x over previous
//
#include <hip/hip_runtime.h>

#define H_ 160
#define W_ 160
#define HW_ (H_ * W_)
#define NPIX (8 * HW_)   // 204800 pixels

// ============================================================================
// R13: R12 with __launch_bounds__(256, 4) — single-variable change.
// R12's (256,5) clamped VGPR to 48: the 8x16B stage-2 gather batch (32 VGPRs)
// + f32x16 acc couldn't be co-resident, compiler serialized loads, per-wave
// ILP collapsed (VALUBusy 31.5->22, dur 82->101 despite occupancy 24->39).
// (256,4) = VGPR cap 128: gathers stay in flight AND 4 blk/CU (2x R11).
//  - one shared weight LDS buffer, refilled between stages (28.2 KB total)
//  - conflict-free b128 weight fill + f32x4 transpose writes (R12, kept)
// Numerics identical to R9/R11/R12 (verified).
// ============================================================================

typedef __attribute__((ext_vector_type(8)))  short  short8;   // 8 bf16
typedef __attribute__((ext_vector_type(4)))  float  f32x4;
typedef __attribute__((ext_vector_type(2)))  float  f32x2;
typedef __attribute__((ext_vector_type(16))) float  f32x16;
typedef __attribute__((ext_vector_type(4)))  unsigned u32x4;

__device__ __forceinline__ unsigned pack2_bf16(float a, float b) {
    unsigned ua = __float_as_uint(a); ua += 0x7fffu + ((ua >> 16) & 1u);
    unsigned ub = __float_as_uint(b); ub += 0x7fffu + ((ub >> 16) & 1u);
    return (ua >> 16) | (ub & 0xffff0000u);
}
__device__ __forceinline__ f32x2 up2(unsigned u) {
    f32x2 r;
    r.x = __uint_as_float(u << 16);
    r.y = __uint_as_float(u & 0xffff0000u);
    return r;
}

// ---- x (B,32,H,W) fp32 -> xT (B,H,W,32) bf16 -------------------------------
__global__ __launch_bounds__(256) void nhwc_bf16(
    const float* __restrict__ x, unsigned short* __restrict__ xT)
{
    const int pix = blockIdx.x * 256 + threadIdx.x;
    const int p = pix % HW_;
    const int b = pix / HW_;
    const float* __restrict__ src = x + (size_t)b * 32 * HW_ + p;
    unsigned* __restrict__ dst = (unsigned*)(xT + (size_t)pix * 32);
    #pragma unroll
    for (int g = 0; g < 16; ++g)
        dst[g] = pack2_bf16(src[(2 * g) * HW_], src[(2 * g + 1) * HW_]);
}

// ---- fused: offset conv + bilinear sampling + dcn GEMM + ReLU --------------
__global__ __launch_bounds__(256, 4) void dcn_fused(
    const unsigned short* __restrict__ xT,   // (8,160,160,32) bf16
    const float* __restrict__ w_off,         // (18, 32, 3, 3)
    const float* __restrict__ b_off,         // (18,)
    const float* __restrict__ w_dcn,         // (32, 32, 3, 3)
    float* __restrict__ out)                 // (8, 32, 160, 160)
{
    // lane-linear B-frags: unit = (tap*2 + kstep)*64 + col + 32*kg,
    // 8 bf16 (16 B) each. ONE buffer, refilled between stages.
    __shared__ __align__(16) unsigned short wsh[9 * 128 * 8];   // 18 KB
    __shared__ float offl[4 * 594];   // per-wave offset transpose, row pad 33
    __shared__ float bl[32];
    const int tid = threadIdx.x;

    // ---- fill stage-1 weights (w_off), one b128 unit per lane-iter --------
    for (int u = tid; u < 1152; u += 256) {
        const int tap = u >> 7, rem = u & 127;
        const int s = rem >> 6, rem2 = rem & 63;
        const int kg = rem2 >> 5, col = rem2 & 31;
        const int cb = s * 16 + kg * 8;
        u32x4 v = {0u, 0u, 0u, 0u};
        if (col < 18) {
            const float* __restrict__ wp = w_off + (size_t)(col * 32 + cb) * 9 + tap;
            v.x = pack2_bf16(wp[0 * 9], wp[1 * 9]);
            v.y = pack2_bf16(wp[2 * 9], wp[3 * 9]);
            v.z = pack2_bf16(wp[4 * 9], wp[5 * 9]);
            v.w = pack2_bf16(wp[6 * 9], wp[7 * 9]);
        }
        *(u32x4*)(wsh + u * 8) = v;
    }
    if (tid < 32) bl[tid] = (tid < 18) ? b_off[tid] : 0.0f;
    __syncthreads();

    const int wave = tid >> 6, lane = tid & 63;
    const int n = lane & 31;          // pixel (A-row m) == out channel (D-col)
    const int hh = lane >> 5;         // k-group
    const int pixbase = blockIdx.x * 128 + wave * 32;
    const int pix = pixbase + n;
    const int w = pix % W_, h = (pix / W_) % H_, b = pix / HW_;
    const unsigned short* __restrict__ xb = xT + (size_t)b * HW_ * 32 + hh * 8;

    // ---------------- stage 1: offset conv GEMM ----------------------------
    {
        f32x16 acc = {};
        const u32x4 z4 = {0u, 0u, 0u, 0u};
        #pragma unroll
        for (int tap = 0; tap < 9; ++tap) {
            const int yy = h - 1 + tap / 3;
            const int xx = w - 1 + tap % 3;
            const bool valid = (yy >= 0) && (yy < H_) && (xx >= 0) && (xx < W_);
            const int idx = min(max(yy, 0), H_ - 1) * W_ + min(max(xx, 0), W_ - 1);
            const unsigned short* __restrict__ px_ = xb + (size_t)idx * 32;
            u32x4 l0 = *(const u32x4*)(px_);
            u32x4 l1 = *(const u32x4*)(px_ + 16);
            l0 = valid ? l0 : z4;
            l1 = valid ? l1 : z4;
            const short8 a0 = __builtin_bit_cast(short8, l0);
            const short8 a1 = __builtin_bit_cast(short8, l1);
            const short8 b0 = *(const short8*)(wsh + ((tap * 2 + 0) * 64 + lane) * 8);
            const short8 b1 = *(const short8*)(wsh + ((tap * 2 + 1) * 64 + lane) * 8);
            acc = __builtin_amdgcn_mfma_f32_32x32x16_bf16(a0, b0, acc, 0, 0, 0);
            acc = __builtin_amdgcn_mfma_f32_32x32x16_bf16(a1, b1, acc, 0, 0, 0);
        }
        // D-layout -> per-wave LDS transpose: [j(18)][pix(32)], row pad 33.
        float* __restrict__ owp = offl + wave * 594;
        if (n < 18) {
            const float bia = bl[n];
            #pragma unroll
            for (int g = 0; g < 4; ++g) {
                f32x4 r;
                #pragma unroll
                for (int i = 0; i < 4; ++i) r[i] = acc[g * 4 + i] + bia;
                *(f32x4*)(owp + n * 33 + 8 * g + 4 * hh) = r;
            }
        }
    }
    __syncthreads();   // stage-1 reads + transpose writes complete

    // ---- refill shared buffer with stage-2 weights (w_dcn) ----------------
    for (int u = tid; u < 1152; u += 256) {
        const int tap = u >> 7, rem = u & 127;
        const int s = rem >> 6, rem2 = rem & 63;
        const int kg = rem2 >> 5, col = rem2 & 31;
        const int cb = s * 16 + kg * 8;
        const float* __restrict__ wp = w_dcn + (size_t)(col * 32 + cb) * 9 + tap;
        u32x4 v;
        v.x = pack2_bf16(wp[0 * 9], wp[1 * 9]);
        v.y = pack2_bf16(wp[2 * 9], wp[3 * 9]);
        v.z = pack2_bf16(wp[4 * 9], wp[5 * 9]);
        v.w = pack2_bf16(wp[6 * 9], wp[7 * 9]);
        *(u32x4*)(wsh + u * 8) = v;
    }
    __syncthreads();

    // ---------------- stage 2: bilinear sampling + dcn GEMM ----------------
    const float* __restrict__ ow = offl + wave * 594;
    f32x16 acc = {};

    #pragma unroll
    for (int tap = 0; tap < 9; ++tap) {
        const float dy = ow[(2 * tap) * 33 + n];
        const float dx = ow[(2 * tap + 1) * 33 + n];
        const float py = (float)(h - 1 + tap / 3) + dy;
        const float px = (float)(w - 1 + tap % 3) + dx;
        const float fy0 = floorf(py), fx0 = floorf(px);
        const float wy1 = py - fy0, wx1 = px - fx0;
        const float wy0 = 1.0f - wy1, wx0 = 1.0f - wx1;
        const int y0 = (int)fy0, x0 = (int)fx0;
        const bool vy0 = (y0 >= 0) && (y0 < H_);
        const bool vy1 = (y0 + 1 >= 0) && (y0 + 1 < H_);
        const bool vx0 = (x0 >= 0) && (x0 < W_);
        const bool vx1 = (x0 + 1 >= 0) && (x0 + 1 < W_);
        const float w00 = (vy0 && vx0) ? wy0 * wx0 : 0.0f;
        const float w01 = (vy0 && vx1) ? wy0 * wx1 : 0.0f;
        const float w10 = (vy1 && vx0) ? wy1 * wx0 : 0.0f;
        const float w11 = (vy1 && vx1) ? wy1 * wx1 : 0.0f;
        const int yc0 = min(max(y0, 0), H_ - 1), yc1 = min(max(y0 + 1, 0), H_ - 1);
        const int xc0 = min(max(x0, 0), W_ - 1), xc1 = min(max(x0 + 1, 0), W_ - 1);

        const unsigned short* __restrict__ pA = xb + (size_t)(yc0 * W_ + xc0) * 32;
        const unsigned short* __restrict__ pB = xb + (size_t)(yc0 * W_ + xc1) * 32;
        const unsigned short* __restrict__ pC = xb + (size_t)(yc1 * W_ + xc0) * 32;
        const unsigned short* __restrict__ pD = xb + (size_t)(yc1 * W_ + xc1) * 32;
        // 8 independent 16B gathers (2 k-steps x 4 corners)
        const u32x4 A0 = *(const u32x4*)(pA);      const u32x4 A1 = *(const u32x4*)(pA + 16);
        const u32x4 B0 = *(const u32x4*)(pB);      const u32x4 B1 = *(const u32x4*)(pB + 16);
        const u32x4 C0 = *(const u32x4*)(pC);      const u32x4 C1 = *(const u32x4*)(pC + 16);
        const u32x4 D0 = *(const u32x4*)(pD);      const u32x4 D1 = *(const u32x4*)(pD + 16);

        #define COMB(a, bb, cc, dd) ({ \
            const f32x2 v = up2(a) * w00 + up2(bb) * w01 + up2(cc) * w10 + up2(dd) * w11; \
            pack2_bf16(v.x, v.y); })
        u32x4 av0, av1;
        av0.x = COMB(A0.x, B0.x, C0.x, D0.x);
        av0.y = COMB(A0.y, B0.y, C0.y, D0.y);
        av0.z = COMB(A0.z, B0.z, C0.z, D0.z);
        av0.w = COMB(A0.w, B0.w, C0.w, D0.w);
        av1.x = COMB(A1.x, B1.x, C1.x, D1.x);
        av1.y = COMB(A1.y, B1.y, C1.y, D1.y);
        av1.z = COMB(A1.z, B1.z, C1.z, D1.z);
        av1.w = COMB(A1.w, B1.w, C1.w, D1.w);
        #undef COMB

        const short8 a0 = __builtin_bit_cast(short8, av0);
        const short8 a1 = __builtin_bit_cast(short8, av1);
        const short8 b0 = *(const short8*)(wsh + ((tap * 2 + 0) * 64 + lane) * 8);
        const short8 b1 = *(const short8*)(wsh + ((tap * 2 + 1) * 64 + lane) * 8);
        acc = __builtin_amdgcn_mfma_f32_32x32x16_bf16(a0, b0, acc, 0, 0, 0);
        acc = __builtin_amdgcn_mfma_f32_32x32x16_bf16(a1, b1, acc, 0, 0, 0);
    }

    // D: col o = n; rows = pixels pixbase + g*8 + 4*hh + i
    float* __restrict__ ob = out + (size_t)b * 32 * HW_ + (size_t)n * HW_
                           + (pixbase - b * HW_) + 4 * hh;
    #pragma unroll
    for (int g = 0; g < 4; ++g) {
        f32x4 r;
        #pragma unroll
        for (int i = 0; i < 4; ++i) r[i] = fmaxf(acc[g * 4 + i], 0.0f);
        *(f32x4*)(ob + g * 8) = r;
    }
}

extern "C" void kernel_launch(void* const* d_in, const int* in_sizes, int n_in,
                              void* d_out, int out_size, void* d_ws, size_t ws_size,
                              hipStream_t stream) {
    const float* x     = (const float*)d_in[0];
    const float* w_off = (const float*)d_in[1];
    const float* b_off = (const float*)d_in[2];
    const float* w_dcn = (const float*)d_in[3];
    float* out = (float*)d_out;

    unsigned short* xT = (unsigned short*)d_ws;   // 13.1 MB bf16 NHWC

    nhwc_bf16<<<800, 256, 0, stream>>>(x, xT);
    dcn_fused<<<1600, 256, 0, stream>>>(xT, w_off, b_off, w_dcn, out);
}

// Round 14
// 163.018 us; speedup vs baseline: 1.0867x; 1.0832x over previous
//
#include <hip/hip_runtime.h>

#define H_ 160
#define W_ 160
#define HW_ (H_ * W_)
#define NPIX (8 * HW_)   // 204800 pixels

// ============================================================================
// R14: R13 with 512-thread blocks (8 waves) -> 800 blocks.
// R13 diagnosis: grid 1600 blocks vs 1280-block residency capacity = 1.25
// dispatch rounds -> occupancy stuck at 39%, latency-bound (VALU 22%, MFMA 3%,
// HBM 8%). 800 blocks @ 4-blocks/CU capacity = single fully-resident round,
// ~25 waves/CU. Compiler ILP is immovable (R5/R8/R13: scheduler re-serializes
// gather batches, VGPR pinned at 48) -> TLP is the only latency lever left.
// Numerics/layout identical to R9..R13 (verified): bf16 MFMA 32x32x16,
// A[m=lane&31][k=(lane>>5)*8+j], D col n=lane&31, row=(reg&3)+8*(reg>>2)
// +4*(lane>>5); shared weight LDS refilled between stages; packed-f32 combine.
// ============================================================================

typedef __attribute__((ext_vector_type(8)))  short  short8;   // 8 bf16
typedef __attribute__((ext_vector_type(4)))  float  f32x4;
typedef __attribute__((ext_vector_type(2)))  float  f32x2;
typedef __attribute__((ext_vector_type(16))) float  f32x16;
typedef __attribute__((ext_vector_type(4)))  unsigned u32x4;

__device__ __forceinline__ unsigned pack2_bf16(float a, float b) {
    unsigned ua = __float_as_uint(a); ua += 0x7fffu + ((ua >> 16) & 1u);
    unsigned ub = __float_as_uint(b); ub += 0x7fffu + ((ub >> 16) & 1u);
    return (ua >> 16) | (ub & 0xffff0000u);
}
__device__ __forceinline__ f32x2 up2(unsigned u) {
    f32x2 r;
    r.x = __uint_as_float(u << 16);
    r.y = __uint_as_float(u & 0xffff0000u);
    return r;
}

// ---- x (B,32,H,W) fp32 -> xT (B,H,W,32) bf16 -------------------------------
__global__ __launch_bounds__(256) void nhwc_bf16(
    const float* __restrict__ x, unsigned short* __restrict__ xT)
{
    const int pix = blockIdx.x * 256 + threadIdx.x;
    const int p = pix % HW_;
    const int b = pix / HW_;
    const float* __restrict__ src = x + (size_t)b * 32 * HW_ + p;
    unsigned* __restrict__ dst = (unsigned*)(xT + (size_t)pix * 32);
    #pragma unroll
    for (int g = 0; g < 16; ++g)
        dst[g] = pack2_bf16(src[(2 * g) * HW_], src[(2 * g + 1) * HW_]);
}

// ---- fused: offset conv + bilinear sampling + dcn GEMM + ReLU --------------
__global__ __launch_bounds__(512, 4) void dcn_fused(
    const unsigned short* __restrict__ xT,   // (8,160,160,32) bf16
    const float* __restrict__ w_off,         // (18, 32, 3, 3)
    const float* __restrict__ b_off,         // (18,)
    const float* __restrict__ w_dcn,         // (32, 32, 3, 3)
    float* __restrict__ out)                 // (8, 32, 160, 160)
{
    // lane-linear B-frags: unit = (tap*2 + kstep)*64 + col + 32*kg,
    // 8 bf16 (16 B) each. ONE buffer, refilled between stages.
    __shared__ __align__(16) unsigned short wsh[9 * 128 * 8];   // 18 KB
    __shared__ float offl[8 * 594];   // per-wave offset transpose, row pad 33
    __shared__ float bl[32];
    const int tid = threadIdx.x;

    // ---- fill stage-1 weights (w_off), one b128 unit per lane-iter --------
    for (int u = tid; u < 1152; u += 512) {
        const int tap = u >> 7, rem = u & 127;
        const int s = rem >> 6, rem2 = rem & 63;
        const int kg = rem2 >> 5, col = rem2 & 31;
        const int cb = s * 16 + kg * 8;
        u32x4 v = {0u, 0u, 0u, 0u};
        if (col < 18) {
            const float* __restrict__ wp = w_off + (size_t)(col * 32 + cb) * 9 + tap;
            v.x = pack2_bf16(wp[0 * 9], wp[1 * 9]);
            v.y = pack2_bf16(wp[2 * 9], wp[3 * 9]);
            v.z = pack2_bf16(wp[4 * 9], wp[5 * 9]);
            v.w = pack2_bf16(wp[6 * 9], wp[7 * 9]);
        }
        *(u32x4*)(wsh + u * 8) = v;
    }
    if (tid < 32) bl[tid] = (tid < 18) ? b_off[tid] : 0.0f;
    __syncthreads();

    const int wave = tid >> 6, lane = tid & 63;   // wave 0..7
    const int n = lane & 31;          // pixel (A-row m) == out channel (D-col)
    const int hh = lane >> 5;         // k-group
    const int pixbase = blockIdx.x * 256 + wave * 32;
    const int pix = pixbase + n;
    const int w = pix % W_, h = (pix / W_) % H_, b = pix / HW_;
    const unsigned short* __restrict__ xb = xT + (size_t)b * HW_ * 32 + hh * 8;

    // ---------------- stage 1: offset conv GEMM ----------------------------
    {
        f32x16 acc = {};
        const u32x4 z4 = {0u, 0u, 0u, 0u};
        #pragma unroll
        for (int tap = 0; tap < 9; ++tap) {
            const int yy = h - 1 + tap / 3;
            const int xx = w - 1 + tap % 3;
            const bool valid = (yy >= 0) && (yy < H_) && (xx >= 0) && (xx < W_);
            const int idx = min(max(yy, 0), H_ - 1) * W_ + min(max(xx, 0), W_ - 1);
            const unsigned short* __restrict__ px_ = xb + (size_t)idx * 32;
            u32x4 l0 = *(const u32x4*)(px_);
            u32x4 l1 = *(const u32x4*)(px_ + 16);
            l0 = valid ? l0 : z4;
            l1 = valid ? l1 : z4;
            const short8 a0 = __builtin_bit_cast(short8, l0);
            const short8 a1 = __builtin_bit_cast(short8, l1);
            const short8 b0 = *(const short8*)(wsh + ((tap * 2 + 0) * 64 + lane) * 8);
            const short8 b1 = *(const short8*)(wsh + ((tap * 2 + 1) * 64 + lane) * 8);
            acc = __builtin_amdgcn_mfma_f32_32x32x16_bf16(a0, b0, acc, 0, 0, 0);
            acc = __builtin_amdgcn_mfma_f32_32x32x16_bf16(a1, b1, acc, 0, 0, 0);
        }
        // D-layout -> per-wave LDS transpose: [j(18)][pix(32)], row pad 33.
        float* __restrict__ owp = offl + wave * 594;
        if (n < 18) {
            const float bia = bl[n];
            #pragma unroll
            for (int g = 0; g < 4; ++g) {
                f32x4 r;
                #pragma unroll
                for (int i = 0; i < 4; ++i) r[i] = acc[g * 4 + i] + bia;
                *(f32x4*)(owp + n * 33 + 8 * g + 4 * hh) = r;
            }
        }
    }
    __syncthreads();   // stage-1 reads + transpose writes complete

    // ---- refill shared buffer with stage-2 weights (w_dcn) ----------------
    for (int u = tid; u < 1152; u += 512) {
        const int tap = u >> 7, rem = u & 127;
        const int s = rem >> 6, rem2 = rem & 63;
        const int kg = rem2 >> 5, col = rem2 & 31;
        const int cb = s * 16 + kg * 8;
        const float* __restrict__ wp = w_dcn + (size_t)(col * 32 + cb) * 9 + tap;
        u32x4 v;
        v.x = pack2_bf16(wp[0 * 9], wp[1 * 9]);
        v.y = pack2_bf16(wp[2 * 9], wp[3 * 9]);
        v.z = pack2_bf16(wp[4 * 9], wp[5 * 9]);
        v.w = pack2_bf16(wp[6 * 9], wp[7 * 9]);
        *(u32x4*)(wsh + u * 8) = v;
    }
    __syncthreads();

    // ---------------- stage 2: bilinear sampling + dcn GEMM ----------------
    const float* __restrict__ ow = offl + wave * 594;
    f32x16 acc = {};

    #pragma unroll
    for (int tap = 0; tap < 9; ++tap) {
        const float dy = ow[(2 * tap) * 33 + n];
        const float dx = ow[(2 * tap + 1) * 33 + n];
        const float py = (float)(h - 1 + tap / 3) + dy;
        const float px = (float)(w - 1 + tap % 3) + dx;
        const float fy0 = floorf(py), fx0 = floorf(px);
        const float wy1 = py - fy0, wx1 = px - fx0;
        const float wy0 = 1.0f - wy1, wx0 = 1.0f - wx1;
        const int y0 = (int)fy0, x0 = (int)fx0;
        const bool vy0 = (y0 >= 0) && (y0 < H_);
        const bool vy1 = (y0 + 1 >= 0) && (y0 + 1 < H_);
        const bool vx0 = (x0 >= 0) && (x0 < W_);
        const bool vx1 = (x0 + 1 >= 0) && (x0 + 1 < W_);
        const float w00 = (vy0 && vx0) ? wy0 * wx0 : 0.0f;
        const float w01 = (vy0 && vx1) ? wy0 * wx1 : 0.0f;
        const float w10 = (vy1 && vx0) ? wy1 * wx0 : 0.0f;
        const float w11 = (vy1 && vx1) ? wy1 * wx1 : 0.0f;
        const int yc0 = min(max(y0, 0), H_ - 1), yc1 = min(max(y0 + 1, 0), H_ - 1);
        const int xc0 = min(max(x0, 0), W_ - 1), xc1 = min(max(x0 + 1, 0), W_ - 1);

        const unsigned short* __restrict__ pA = xb + (size_t)(yc0 * W_ + xc0) * 32;
        const unsigned short* __restrict__ pB = xb + (size_t)(yc0 * W_ + xc1) * 32;
        const unsigned short* __restrict__ pC = xb + (size_t)(yc1 * W_ + xc0) * 32;
        const unsigned short* __restrict__ pD = xb + (size_t)(yc1 * W_ + xc1) * 32;
        // 8 independent 16B gathers (2 k-steps x 4 corners)
        const u32x4 A0 = *(const u32x4*)(pA);      const u32x4 A1 = *(const u32x4*)(pA + 16);
        const u32x4 B0 = *(const u32x4*)(pB);      const u32x4 B1 = *(const u32x4*)(pB + 16);
        const u32x4 C0 = *(const u32x4*)(pC);      const u32x4 C1 = *(const u32x4*)(pC + 16);
        const u32x4 D0 = *(const u32x4*)(pD);      const u32x4 D1 = *(const u32x4*)(pD + 16);

        #define COMB(a, bb, cc, dd) ({ \
            const f32x2 v = up2(a) * w00 + up2(bb) * w01 + up2(cc) * w10 + up2(dd) * w11; \
            pack2_bf16(v.x, v.y); })
        u32x4 av0, av1;
        av0.x = COMB(A0.x, B0.x, C0.x, D0.x);
        av0.y = COMB(A0.y, B0.y, C0.y, D0.y);
        av0.z = COMB(A0.z, B0.z, C0.z, D0.z);
        av0.w = COMB(A0.w, B0.w, C0.w, D0.w);
        av1.x = COMB(A1.x, B1.x, C1.x, D1.x);
        av1.y = COMB(A1.y, B1.y, C1.y, D1.y);
        av1.z = COMB(A1.z, B1.z, C1.z, D1.z);
        av1.w = COMB(A1.w, B1.w, C1.w, D1.w);
        #undef COMB

        const short8 a0 = __builtin_bit_cast(short8, av0);
        const short8 a1 = __builtin_bit_cast(short8, av1);
        const short8 b0 = *(const short8*)(wsh + ((tap * 2 + 0) * 64 + lane) * 8);
        const short8 b1 = *(const short8*)(wsh + ((tap * 2 + 1) * 64 + lane) * 8);
        acc = __builtin_amdgcn_mfma_f32_32x32x16_bf16(a0, b0, acc, 0, 0, 0);
        acc = __builtin_amdgcn_mfma_f32_32x32x16_bf16(a1, b1, acc, 0, 0, 0);
    }

    // D: col o = n; rows = pixels pixbase + g*8 + 4*hh + i
    float* __restrict__ ob = out + (size_t)b * 32 * HW_ + (size_t)n * HW_
                           + (pixbase - b * HW_) + 4 * hh;
    #pragma unroll
    for (int g = 0; g < 4; ++g) {
        f32x4 r;
        #pragma unroll
        for (int i = 0; i < 4; ++i) r[i] = fmaxf(acc[g * 4 + i], 0.0f);
        *(f32x4*)(ob + g * 8) = r;
    }
}

extern "C" void kernel_launch(void* const* d_in, const int* in_sizes, int n_in,
                              void* d_out, int out_size, void* d_ws, size_t ws_size,
                              hipStream_t stream) {
    const float* x     = (const float*)d_in[0];
    const float* w_off = (const float*)d_in[1];
    const float* b_off = (const float*)d_in[2];
    const float* w_dcn = (const float*)d_in[3];
    float* out = (float*)d_out;

    unsigned short* xT = (unsigned short*)d_ws;   // 13.1 MB bf16 NHWC

    nhwc_bf16<<<800, 256, 0, stream>>>(x, xT);
    dcn_fused<<<800, 512, 0, stream>>>(xT, w_off, b_off, w_dcn, out);
}